// Round 2
// baseline (113.107 us; speedup 1.0000x reference)
//
#include <hip/hip_runtime.h>

#define NF    50000
#define PADP  50001
#define KN    9
#define KTOT  2304
#define NCHUNK 782
#define NT    72          // 2304 / 32
#define BM    112
#define NBLK  447         // ceil(50000/112)

// ---- ws layout (bytes) ----
#define WT_OFF   0u          // 256*2304*2 = 1179648
#define FLAG_OFF 1179648u    // 4
#define CNT_OFF  1179904u    // 782*4
#define PADX_OFF 1183744u    // 50001*256*2 = 25600512

typedef float f32x4 __attribute__((ext_vector_type(4)));
typedef __bf16 bf16x8 __attribute__((ext_vector_type(8)));

typedef const __attribute__((address_space(1))) unsigned int* gas_t;
typedef __attribute__((address_space(3))) unsigned int* las_t;

static __device__ __forceinline__ void gll16(const void* g, void* l) {
  __builtin_amdgcn_global_load_lds((gas_t)g, (las_t)l, 16, 0, 0);
}

static __device__ __forceinline__ unsigned short f2bf(float f) {
  unsigned int u = __builtin_bit_cast(unsigned int, f);
  u = u + 0x7fffu + ((u >> 16) & 1u);      // RNE
  return (unsigned short)(u >> 16);
}

// ---------- preprocessing ----------

// Per-64-chunk pad counts + int64-vs-int32 detection for face_neighborhood.
__global__ void k_pre1(const unsigned char* __restrict__ pad, int* __restrict__ cnt,
                       const unsigned int* __restrict__ raw, int* __restrict__ flag) {
  int t = blockIdx.x * 256 + threadIdx.x;
  bool ip = (t < PADP) ? (pad[t] != 0) : true;
  unsigned long long m = __ballot(ip);
  int c = t >> 6;
  if ((threadIdx.x & 63) == 0 && c < NCHUNK) cnt[c] = __popcll(m);
  if (blockIdx.x == 0 && threadIdx.x < 64) {
    unsigned int v = raw[threadIdx.x * 2 + 1];
    unsigned long long nz = __ballot(v != 0u);
    if (threadIdx.x == 0) flag[0] = (nz == 0ull) ? 1 : 0;
  }
}

// Demodulate weight and transpose to wt[o][k*256+i] (bf16).
__global__ void k_wt(const float* __restrict__ w, unsigned short* __restrict__ wt) {
  int o = blockIdx.x;
  int i = threadIdx.x;
  const float* wr = w + (o * 256 + i) * 9;
  float wv[9];
  float s = 0.f;
#pragma unroll
  for (int k = 0; k < 9; ++k) { wv[k] = wr[k]; s += wv[k] * wv[k]; }
#pragma unroll
  for (int d = 32; d >= 1; d >>= 1) s += __shfl_xor(s, d);
  __shared__ float red[4];
  if ((i & 63) == 0) red[i >> 6] = s;
  __syncthreads();
  float dc = rsqrtf(red[0] + red[1] + red[2] + red[3] + 1e-8f);
#pragma unroll
  for (int k = 0; k < 9; ++k)
    wt[o * KTOT + k * 256 + i] = f2bf(wv[k] * dc);
}

// Fused: per-block prefix over cnt -> ballot ranks -> padded_x bf16 conversion.
__global__ __launch_bounds__(256) void k_rankpadx(
    const float* __restrict__ x, const unsigned char* __restrict__ pad,
    const int* __restrict__ cnt, unsigned short* __restrict__ padx) {
  const int b = blockIdx.x;
  const int tid = threadIdx.x, w = tid >> 6, lane = tid & 63;
  const int p0 = b * 256;
  // prefix pads in chunks before this block
  int s = 0;
  for (int i = tid; i < b * 4; i += 256) s += cnt[i];
#pragma unroll
  for (int d = 32; d >= 1; d >>= 1) s += __shfl_xor(s, d);
  __shared__ int ws4[4], wpads[4], rnk[256];
  // ballot this block's rows
  int p = p0 + w * 64 + lane;
  bool ip = (p < PADP) ? (pad[p] != 0) : true;
  unsigned long long m = __ballot(ip);
  if (lane == 0) { ws4[w] = s; wpads[w] = __popcll(m); }
  __syncthreads();
  int base_pads = ws4[0] + ws4[1] + ws4[2] + ws4[3];
  int wbefore = 0;
#pragma unroll
  for (int i = 0; i < 4; ++i) if (i < w) wbefore += wpads[i];
  int before = __popcll(m & ((1ull << lane) - 1ull));
  rnk[w * 64 + lane] = ip ? -1 : (p - (base_pads + wbefore + before));
  __syncthreads();
  // convert rows
  const int c = lane * 4;
  for (int i = 0; i < 64; ++i) {
    int rl = i * 4 + w;
    int pp = p0 + rl;
    if (pp >= PADP) continue;
    int rr = rnk[rl];
    ushort4 ov;
    if (rr < 0) { ov.x = 0; ov.y = 0; ov.z = 0; ov.w = 0; }
    else {
      const float4 v = *(const float4*)(x + rr * 256 + c);
      ov.x = f2bf(v.x); ov.y = f2bf(v.y); ov.z = f2bf(v.z); ov.w = f2bf(v.w);
    }
    *(ushort4*)(padx + pp * 256 + c) = ov;
  }
}

// ---------- main gathered GEMM ----------
// BM=112 x BN=256 x BK=32, 4 waves (1M x 4N), wave-tile 112x64 (7x4 frags).
// LDS: 2 buffers x (A 112x32 @0 (7168B) + B 256x32 @7168 (16384B)) = 47104B.
// Double-buffered, front-loaded next-tile staging (full-tile lead), 2 blocks/CU.
__global__ __launch_bounds__(256, 2) void k_main(
    const unsigned short* __restrict__ padx,   // [50001][256] bf16
    const unsigned short* __restrict__ wt,     // [256][2304] bf16
    const void* __restrict__ nbr,              // [50000][9] int64 or int32
    const int* __restrict__ flag,
    const float* __restrict__ bias,            // [256]
    float* __restrict__ out) {                 // [50000][256] f32
  __shared__ __align__(16) unsigned char sm[2][23552];
  const int tid = threadIdx.x;
  const int w = tid >> 6, lane = tid & 63;
  const int m0 = blockIdx.x * BM;
  const bool f64 = (flag[0] != 0);
  const long long* n64 = (const long long*)nbr;
  const int* n32 = (const int*)nbr;

  // staging constants: rows of 64B (32 bf16), 4 lanes/row, swizzled source slot
  const int sw8 = ((tid ^ (tid >> 2) ^ (tid >> 4)) & 3) * 8;  // elems
  int faceA0 = m0 + (tid >> 2);        if (faceA0 > NF - 1) faceA0 = NF - 1;
  int faceA1 = m0 + 64 + (tid >> 2);   if (faceA1 > NF - 1) faceA1 = NF - 1;
  const int ldsA0 = w * 1024;          // A round j: + j*4096
  const int ldsB0 = 7168 + w * 1024;   // B round j: + j*4096
  int gB[4];
#pragma unroll
  for (int j = 0; j < 4; ++j) gB[j] = (j * 64 + (tid >> 2)) * KTOT + sw8;

  // fragment read offsets (bytes within one buffer)
  const int q = lane & 15, hi = lane >> 4;
  const int fq = (q ^ (q >> 2)) & 3;
  const int slotb = (hi ^ fq) * 16;
  int aoff[7], boff[4];
#pragma unroll
  for (int mi = 0; mi < 7; ++mi) aoff[mi] = (mi * 16 + q) * 64 + slotb;
#pragma unroll
  for (int ni = 0; ni < 4; ++ni) boff[ni] = 7168 + (w * 64 + ni * 16 + q) * 64 + slotb;

  f32x4 acc[7][4];
#pragma unroll
  for (int a = 0; a < 7; ++a)
#pragma unroll
    for (int b = 0; b < 4; ++b) {
      acc[a][b][0] = 0.f; acc[a][b][1] = 0.f; acc[a][b][2] = 0.f; acc[a][b][3] = 0.f;
    }

  int idxcur0, idxcur1, idxnxt0, idxnxt1;
  if (f64) { idxcur0 = (int)n64[faceA0 * KN]; idxcur1 = (int)n64[faceA1 * KN]; }
  else     { idxcur0 = n32[faceA0 * KN];      idxcur1 = n32[faceA1 * KN]; }
  idxnxt0 = idxcur0; idxnxt1 = idxcur1;

  // prologue: stage tile 0 into buf 0 (neighbor 0, channels 0..31)
  gll16(padx + idxcur0 * 256 + sw8, &sm[0][0] + ldsA0);
  if (tid < 192) gll16(padx + idxcur1 * 256 + sw8, &sm[0][0] + 4096 + ldsA0);
#pragma unroll
  for (int j = 0; j < 4; ++j)
    gll16(wt + gB[j], &sm[0][0] + ldsB0 + j * 4096);
  __syncthreads();

  for (int nb = 0; nb < 9; ++nb) {
#pragma unroll
    for (int qq = 0; qq < 8; ++qq) {
      const int t = nb * 8 + qq;
      const int u = t + 1;
      unsigned char* cur = &sm[t & 1][0];
      unsigned char* nxt = &sm[u & 1][0];
      // front-load staging of tile u (full-tile lead before the drain)
      if (u < NT) {
        const int kc = (u & 7) * 32;              // channel offset within padx row
        const int kg = (u >> 3) * 256 + kc;       // global k for wt
        const int iv0 = (qq == 7) ? idxnxt0 : idxcur0;
        const int iv1 = (qq == 7) ? idxnxt1 : idxcur1;
        gll16(padx + iv0 * 256 + kc + sw8, nxt + ldsA0);
        if (tid < 192) gll16(padx + iv1 * 256 + kc + sw8, nxt + 4096 + ldsA0);
#pragma unroll
        for (int j = 0; j < 4; ++j)
          gll16(wt + gB[j] + kg, nxt + ldsB0 + j * 4096);
      }
      // prefetch next neighbor's gather indices (7 tiles of slack)
      if (qq == 0 && nb < 8) {
        if (f64) { idxnxt0 = (int)n64[faceA0 * KN + nb + 1]; idxnxt1 = (int)n64[faceA1 * KN + nb + 1]; }
        else     { idxnxt0 = n32[faceA0 * KN + nb + 1];      idxnxt1 = n32[faceA1 * KN + nb + 1]; }
      }
      // compute tile t
      bf16x8 bf[4];
#pragma unroll
      for (int ni = 0; ni < 4; ++ni) bf[ni] = *(const bf16x8*)(cur + boff[ni]);
      __builtin_amdgcn_s_setprio(1);
#pragma unroll
      for (int mi = 0; mi < 7; ++mi) {
        bf16x8 af = *(const bf16x8*)(cur + aoff[mi]);
#pragma unroll
        for (int ni = 0; ni < 4; ++ni)
          acc[mi][ni] = __builtin_amdgcn_mfma_f32_16x16x32_bf16(af, bf[ni], acc[mi][ni], 0, 0, 0);
      }
      __builtin_amdgcn_s_setprio(0);
      __syncthreads();
    }
    idxcur0 = idxnxt0;
    idxcur1 = idxnxt1;
  }

  // epilogue: bias + store (D: col = lane&15, row = (lane>>4)*4 + r)
#pragma unroll
  for (int ni = 0; ni < 4; ++ni) {
    const int col = w * 64 + ni * 16 + q;
    const float bv = bias[col];
#pragma unroll
    for (int mi = 0; mi < 7; ++mi) {
#pragma unroll
      for (int r = 0; r < 4; ++r) {
        const int row = m0 + mi * 16 + hi * 4 + r;
        if (row < NF) out[row * 256 + col] = acc[mi][ni][r] + bv;
      }
    }
  }
}

extern "C" void kernel_launch(void* const* d_in, const int* in_sizes, int n_in,
                              void* d_out, int out_size, void* d_ws, size_t ws_size,
                              hipStream_t stream) {
  const float* x = (const float*)d_in[0];
  const float* wfull = (const float*)d_in[1];
  const float* bias = (const float*)d_in[2];
  const void* nbr = d_in[3];
  const unsigned char* pad = (const unsigned char*)d_in[4];
  float* out = (float*)d_out;
  char* ws = (char*)d_ws;

  unsigned short* wt   = (unsigned short*)(ws + WT_OFF);
  int* flag            = (int*)(ws + FLAG_OFF);
  int* cnt             = (int*)(ws + CNT_OFF);
  unsigned short* padx = (unsigned short*)(ws + PADX_OFF);

  k_pre1<<<196, 256, 0, stream>>>(pad, cnt, (const unsigned int*)nbr, flag);
  k_wt<<<256, 256, 0, stream>>>(wfull, wt);
  k_rankpadx<<<196, 256, 0, stream>>>(x, pad, cnt, padx);
  k_main<<<NBLK, 256, 0, stream>>>(padx, wt, nbr, flag, bias, out);
}